// Round 2
// baseline (991.368 us; speedup 1.0000x reference)
//
#include <hip/hip_runtime.h>

// Moreau-tropical forward, thread-per-(b,n) streaming formulation.
//
// f(tau) = sum_d relu(z_d - tau), z = x[b] + W[n].  f(M - lam) >= lam where
// M = max(z), so the root lies in [M - lam, M] and only z > M - lam matter.
// Each THREAD owns one (b,n) pair: stream z over LDS-staged chunks, track max
// with 4 rotating partials, collect candidates z > runningMax - lam into a
// per-thread LDS buffer (lazy compaction; stale entries <= M - lam contribute 0
// in the bisection, so no final prune needed). Then bisect per-thread over <=16
// register-resident candidates: no shuffles, no atomics, no cross-lane deps.

#define D_DIM    1024
#define CHUNK    128
#define CPAD     (CHUNK + 4)   // row stride 132 floats = 528 B: 16B-aligned, stride%32=4 -> <=2-way alias on b128 (free)
#define TB       8
#define TN       32
#define NTHREADS (TB * TN)     // 256
#define CAP      16
#define NB       22            // bisection iters on width-lam interval; y is 2nd-order insensitive to tau
#define NEG_INF  (-3.0e38f)

__global__ void __launch_bounds__(NTHREADS)
moreau_tropical(const float* __restrict__ x, const float* __restrict__ W,
                const float* __restrict__ lam_p, float* __restrict__ out,
                int B, int N) {
    __shared__ float xs[TB][CPAD];
    __shared__ float ws[TN][CPAD];
    __shared__ float cand[CAP * NTHREADS];   // cand[k*256 + tid]: lanes -> consecutive banks

    const int tid = threadIdx.x;
    const int tn  = tid & (TN - 1);
    const int tb  = tid >> 5;
    const int b0  = blockIdx.y * TB;
    const int n0  = blockIdx.x * TN;
    int b = b0 + tb; if (b >= B) b = B - 1;   // clamp: duplicate threads compute identical value
    int n = n0 + tn; if (n >= N) n = N - 1;

    const float lam = lam_p[0];

    float m0 = NEG_INF, m1 = NEG_INF, m2 = NEG_INF, m3 = NEG_INF;
    float thr = NEG_INF;     // insert threshold; monotone non-decreasing
    int   cnt = 0;
    bool  overflow = false;

    for (int d0 = 0; d0 < D_DIM; d0 += CHUNK) {
        __syncthreads();
        {   // stage x tile: 8 rows x 128 cols = 256 float4, one per thread (coalesced)
            const int row = tid >> 5;
            const int c4  = tid & 31;
            int gr = b0 + row; if (gr >= B) gr = B - 1;
            *(float4*)&xs[row][c4 * 4] =
                *(const float4*)(x + (size_t)gr * D_DIM + d0 + c4 * 4);
        }
#pragma unroll
        for (int i = 0; i < 4; ++i) {   // stage W tile: 32 rows x 128 cols = 1024 float4
            const int idx = tid + NTHREADS * i;
            const int row = idx >> 5;
            const int c4  = idx & 31;
            int gr = n0 + row; if (gr >= N) gr = N - 1;
            *(float4*)&ws[row][c4 * 4] =
                *(const float4*)(W + (size_t)gr * D_DIM + d0 + c4 * 4);
        }
        __syncthreads();

        for (int dd = 0; dd < CHUNK; dd += 16) {
            float zg[16];
#pragma unroll
            for (int g = 0; g < 4; ++g) {
                const float4 wv = *(const float4*)&ws[tn][dd + g * 4];
                const float4 xv = *(const float4*)&xs[tb][dd + g * 4];
                const float z0 = xv.x + wv.x;
                const float z1 = xv.y + wv.y;
                const float z2 = xv.z + wv.z;
                const float z3 = xv.w + wv.w;
                zg[g * 4 + 0] = z0; zg[g * 4 + 1] = z1;
                zg[g * 4 + 2] = z2; zg[g * 4 + 3] = z3;
                const float gm = fmaxf(fmaxf(z0, z1), fmaxf(z2, z3));
                if (g == 0) m0 = fmaxf(m0, gm);
                else if (g == 1) m1 = fmaxf(m1, gm);
                else if (g == 2) m2 = fmaxf(m2, gm);
                else m3 = fmaxf(m3, gm);
            }
            // refresh threshold with THIS group's max included -> minimal inserts
            const float curmax = fmaxf(fmaxf(m0, m1), fmaxf(m2, m3));
            thr = fmaxf(thr, curmax - lam);
#pragma unroll
            for (int k = 0; k < 16; ++k) {
                if (zg[k] > thr) {               // rare: exec-mask branch
                    cand[cnt * NTHREADS + tid] = zg[k];
                    ++cnt;
                    if (cnt == CAP) {            // lazy compaction against fresh thr
                        int nc = 0;
                        for (int q = 0; q < CAP; ++q) {
                            const float v = cand[q * NTHREADS + tid];
                            if (v > thr) { cand[nc * NTHREADS + tid] = v; ++nc; }
                        }
                        cnt = nc;
                        if (cnt == CAP) { overflow = true; thr = 3.0e38f; }
                    }
                }
            }
        }
    }

    const float M = fmaxf(fmaxf(m0, m1), fmaxf(m2, m3));
    float tau, delta;

    if (!overflow) {
        float c[CAP];
#pragma unroll
        for (int k = 0; k < CAP; ++k)
            c[k] = (k < cnt) ? cand[k * NTHREADS + tid] : NEG_INF;

        float lo = M - lam, hi = M;
#pragma unroll
        for (int it = 0; it < NB; ++it) {
            const float mid = 0.5f * (lo + hi);
            float f0 = 0.0f, f1 = 0.0f, f2 = 0.0f, f3 = 0.0f;
#pragma unroll
            for (int k = 0; k < CAP; k += 4) {
                f0 += fmaxf(c[k + 0] - mid, 0.0f);
                f1 += fmaxf(c[k + 1] - mid, 0.0f);
                f2 += fmaxf(c[k + 2] - mid, 0.0f);
                f3 += fmaxf(c[k + 3] - mid, 0.0f);
            }
            const float f = (f0 + f1) + (f2 + f3);
            if (f > lam) lo = mid; else hi = mid;
        }
        tau = 0.5f * (lo + hi);
        float s2 = 0.0f;
#pragma unroll
        for (int k = 0; k < CAP; ++k) {
            const float s = fmaxf(c[k] - tau, 0.0f);
            s2 += s * s;
        }
        delta = s2 / (2.0f * lam);
    } else {
        // statistically-never fallback: per-thread full bisection streaming from global (L2-hot)
        const float* xr = x + (size_t)b * D_DIM;
        const float* wr = W + (size_t)n * D_DIM;
        float lo = M - lam, hi = M;
        for (int it = 0; it < 32; ++it) {
            const float mid = 0.5f * (lo + hi);
            float f = 0.0f;
            for (int d = 0; d < D_DIM; ++d) f += fmaxf(xr[d] + wr[d] - mid, 0.0f);
            if (f > lam) lo = mid; else hi = mid;
        }
        tau = 0.5f * (lo + hi);
        float s2 = 0.0f;
        for (int d = 0; d < D_DIM; ++d) {
            const float s = fmaxf(xr[d] + wr[d] - tau, 0.0f);
            s2 += s * s;
        }
        delta = s2 / (2.0f * lam);
    }

    out[(size_t)b * N + n] = tau + delta;
}

extern "C" void kernel_launch(void* const* d_in, const int* in_sizes, int n_in,
                              void* d_out, int out_size, void* d_ws, size_t ws_size,
                              hipStream_t stream) {
    const float* x    = (const float*)d_in[0];
    const float* W    = (const float*)d_in[1];
    const float* lamp = (const float*)d_in[2];
    float* out        = (float*)d_out;

    const int B = in_sizes[0] / D_DIM;
    const int N = in_sizes[1] / D_DIM;

    dim3 grid((N + TN - 1) / TN, (B + TB - 1) / TB);
    moreau_tropical<<<grid, NTHREADS, 0, stream>>>(x, W, lamp, out, B, N);
}

// Round 3
// 707.612 us; speedup vs baseline: 1.4010x; 1.4010x over previous
//
#include <hip/hip_runtime.h>

// Moreau-tropical forward, round 3: 4-threads-per-pair streaming + per-thread
// LDS candidate buckets + thread-per-pair register solve.
//
// f(tau) = sum_d relu(z_d - tau), z = x[b] + W[n]; root in [M - lam, M] where
// M = max_d z. Only z > M - lam matter (typically 1-8 of 1024).
// Phase A: thread = (pair, d-quarter): stream z from LDS tiles, running max m,
//   insert z > m - lam into own bucket (cap 12, lazy compaction vs fresh m-lam).
//   Guarantee: every final candidate is inserted (test thr <= final thr) and
//   never evicted (eviction thr <= final thr); else bucket flagged overflow.
// Phase C: thread-per-pair: M = max of 4 quarter-maxes; bisect over all 48
//   bucket entries in registers — stale entries <= M-lam contribute exactly 0
//   since every mid >= M-lam, so no filtering/compaction needed. Exact.

#define D_DIM   1024
#define CH      128            // d-chunk staged per iteration
#define CPAD    132            // padded LDS row stride (floats); 528B, 16B-aligned
#define TBP     8              // b rows per block
#define TNP     8              // n cols per block
#define TD      4              // d-slices (threads) per pair
#define NTHR    256            // TBP*TNP*TD
#define CAP     12             // per-thread bucket capacity
#define NB      18             // bisection iters on width-lam interval
#define NEG_INF (-3.0e38f)

__global__ void __launch_bounds__(NTHR, 4)
moreau_tropical(const float* __restrict__ x, const float* __restrict__ W,
                const float* __restrict__ lam_p, float* __restrict__ out,
                int B, int N) {
    __shared__ float xs[TBP][CPAD];
    __shared__ float ws_[TNP][CPAD];
    __shared__ float cand[NTHR * CAP];
    __shared__ float qmax[NTHR];
    __shared__ int   over[NTHR];

    const int tid = threadIdx.x;
    const int q   = tid >> 6;          // wave index = d-quarter (wave-uniform)
    const int p   = tid & 63;          // pair id within tile
    const int pb  = p >> 3;
    const int pn  = p & 7;
    const int b0  = blockIdx.y * TBP;
    const int n0  = blockIdx.x * TNP;
    const int bucket = tid * CAP;
    const int dq  = q * (CH / TD);     // 32*q: this thread's slice within a chunk

    const float lam = lam_p[0];

    float m   = NEG_INF;
    int   cnt = 0;
    int   ovf = 0;

#define INS(v)                                                        \
    do {                                                              \
        if ((v) > tthr && cnt < CAP) {                                \
            cand[bucket + cnt] = (v); ++cnt;                          \
            if (cnt == CAP) {                                         \
                const float ct = m - lam; int nc = 0;                 \
                for (int j = 0; j < CAP; ++j) {                       \
                    const float u = cand[bucket + j];                 \
                    if (u > ct) { cand[bucket + nc] = u; ++nc; }      \
                }                                                     \
                cnt = nc; if (cnt == CAP) ovf = 1;                    \
            }                                                         \
        }                                                             \
    } while (0)

    for (int d0 = 0; d0 < D_DIM; d0 += CH) {
        __syncthreads();   // previous chunk's readers done before restaging
        {
            const int row = tid >> 5;          // 0..7
            const int c4  = (tid & 31) << 2;   // 0,4,...,124
            const int gb  = min(b0 + row, B - 1);
            const int gn  = min(n0 + row, N - 1);
            *(float4*)&xs[row][c4]  = *(const float4*)(x + (size_t)gb * D_DIM + d0 + c4);
            *(float4*)&ws_[row][c4] = *(const float4*)(W + (size_t)gn * D_DIM + d0 + c4);
        }
        __syncthreads();

#pragma unroll
        for (int g = 0; g < CH / TD; g += 4) {
            const float4 xv = *(const float4*)&xs[pb][dq + g];
            const float4 wv = *(const float4*)&ws_[pn][dq + g];
            const float z0 = xv.x + wv.x;
            const float z1 = xv.y + wv.y;
            const float z2 = xv.z + wv.z;
            const float z3 = xv.w + wv.w;
            const float gm = fmaxf(fmaxf(z0, z1), fmaxf(z2, z3));
            const float tthr = m - lam;   // pre-group threshold (<= final thr: superset, safe)
            m = fmaxf(m, gm);
            if (gm > tthr) { INS(z0); INS(z1); INS(z2); INS(z3); }
        }
    }
#undef INS

    qmax[tid] = m;
    over[tid] = ovf;
    for (int j = cnt; j < CAP; ++j) cand[bucket + j] = NEG_INF;
    __syncthreads();

    if (tid < TBP * TNP) {
        const int pbc = tid >> 3;
        const int pnc = tid & 7;

        float M  = qmax[tid];
        int  bad = over[tid];
#pragma unroll
        for (int qq = 1; qq < TD; ++qq) {
            M    = fmaxf(M, qmax[qq * 64 + tid]);
            bad |= over[qq * 64 + tid];
        }
        const float thr = M - lam;
        float tau, delta;

        if (!bad) {
            float c[TD * CAP];   // 48, statically indexed (no scratch spill)
#pragma unroll
            for (int qq = 0; qq < TD; ++qq)
#pragma unroll
                for (int j = 0; j < CAP; ++j)
                    c[qq * CAP + j] = cand[(qq * 64 + tid) * CAP + j];

            float lo = thr, hi = M;
#pragma unroll 1
            for (int it = 0; it < NB; ++it) {
                const float mid = 0.5f * (lo + hi);
                float f0 = 0.f, f1 = 0.f, f2 = 0.f, f3 = 0.f;
#pragma unroll
                for (int j = 0; j < TD * CAP; j += 4) {
                    f0 += fmaxf(c[j + 0] - mid, 0.f);
                    f1 += fmaxf(c[j + 1] - mid, 0.f);
                    f2 += fmaxf(c[j + 2] - mid, 0.f);
                    f3 += fmaxf(c[j + 3] - mid, 0.f);
                }
                const float f = (f0 + f1) + (f2 + f3);
                if (f > lam) lo = mid; else hi = mid;
            }
            tau = 0.5f * (lo + hi);
            float s0 = 0.f, s1 = 0.f, s2 = 0.f, s3 = 0.f;
#pragma unroll
            for (int j = 0; j < TD * CAP; j += 4) {
                const float a0 = fmaxf(c[j + 0] - tau, 0.f);
                const float a1 = fmaxf(c[j + 1] - tau, 0.f);
                const float a2 = fmaxf(c[j + 2] - tau, 0.f);
                const float a3 = fmaxf(c[j + 3] - tau, 0.f);
                s0 += a0 * a0; s1 += a1 * a1; s2 += a2 * a2; s3 += a3 * a3;
            }
            delta = ((s0 + s1) + (s2 + s3)) / (2.f * lam);
        } else {
            // correctness fallback (statistically never): stream from global (L2-hot)
            const float* xr = x + (size_t)min(b0 + pbc, B - 1) * D_DIM;
            const float* wr = W + (size_t)min(n0 + pnc, N - 1) * D_DIM;
            float lo = thr, hi = M;
            for (int it = 0; it < NB; ++it) {
                const float mid = 0.5f * (lo + hi);
                float f = 0.f;
                for (int d = 0; d < D_DIM; ++d) f += fmaxf(xr[d] + wr[d] - mid, 0.f);
                if (f > lam) lo = mid; else hi = mid;
            }
            tau = 0.5f * (lo + hi);
            float s2 = 0.f;
            for (int d = 0; d < D_DIM; ++d) {
                const float s = fmaxf(xr[d] + wr[d] - tau, 0.f);
                s2 += s * s;
            }
            delta = s2 / (2.f * lam);
        }

        const int ob = min(b0 + pbc, B - 1);
        const int on = min(n0 + pnc, N - 1);
        out[(size_t)ob * N + on] = tau + delta;
    }
}

extern "C" void kernel_launch(void* const* d_in, const int* in_sizes, int n_in,
                              void* d_out, int out_size, void* d_ws, size_t ws_size,
                              hipStream_t stream) {
    const float* x    = (const float*)d_in[0];
    const float* W    = (const float*)d_in[1];
    const float* lamp = (const float*)d_in[2];
    float* out        = (float*)d_out;

    const int B = in_sizes[0] / D_DIM;
    const int N = in_sizes[1] / D_DIM;

    dim3 grid((N + TNP - 1) / TNP, (B + TBP - 1) / TBP);
    moreau_tropical<<<grid, NTHR, 0, stream>>>(x, W, lamp, out, B, N);
}

// Round 4
// 103.639 us; speedup vs baseline: 9.5656x; 6.8277x over previous
//
#include <hip/hip_runtime.h>

// Moreau-tropical forward, round 4: exact-threshold two-pass + per-pair solve.
//
// z = x[b] + W[n] (D=1024); root of f(tau)=sum relu(z-tau)=lam lies in
// [M-lam, M], M = max(z). Only z > M-lam contribute to any f(mid) evaluated
// there (mid > M-lam strictly), so pass 1 finds M, pass 2 collects the ~3.5
// candidates per pair with the EXACT threshold (inserts rare -> cheap), and a
// per-pair thread bisects over the candidates. No running-threshold insert
// storms (round-3 failure), no per-pair shuffle-chain bisection (round-1
// failure), feeds are conflict-free broadcast LDS reads.

#define D_DIM   1024
#define TBP     8
#define TNP     8
#define NPAIR   64            // pairs per block
#define NTHR    256           // 4 d-quarter threads per pair
#define QLEN    256           // d-elements per thread
#define XSTR    1028          // LDS row stride (floats): rows 0..7 -> bank offsets 4r, b128 reads cover all 32 banks
#define CAPP    32            // candidate cap per pair (P(genuine>32) ~ 1e-9/pair)
#define NB      20            // bisection iters on width-lam interval
#define NEG_INF (-3.0e38f)

__global__ void __launch_bounds__(NTHR)
moreau_tropical(const float* __restrict__ x, const float* __restrict__ W,
                const float* __restrict__ lam_p, float* __restrict__ out,
                int B, int N) {
    __shared__ float xs[TBP * XSTR];
    __shared__ float ws[TNP * XSTR];
    __shared__ float cand[CAPP * NPAIR];   // cand[j*64 + p]
    __shared__ float qmax[NTHR];
    __shared__ int   pcnt[NPAIR];

    const int tid = threadIdx.x;
    const int q   = tid >> 6;          // d-quarter (wave-uniform)
    const int p   = tid & 63;          // pair id
    const int pb  = p >> 3;
    const int pn  = p & 7;
    const int b0  = blockIdx.y * TBP;
    const int n0  = blockIdx.x * TNP;

    const float lam = lam_p[0];

    // ---- stage full tiles (one-time, coalesced 16B loads) ----
    {
        const int r  = tid >> 5;       // 0..7
        const int c0 = tid & 31;       // 0..31
        const int gb = min(b0 + r, B - 1);
        const int gn = min(n0 + r, N - 1);
        const float* xg = x + (size_t)gb * D_DIM;
        const float* wg = W + (size_t)gn * D_DIM;
        float* xd = xs + r * XSTR;
        float* wd = ws + r * XSTR;
#pragma unroll
        for (int i = 0; i < 8; ++i) {
            const int c4 = (c0 + i * 32) * 4;
            *(float4*)&xd[c4] = *(const float4*)&xg[c4];
            *(float4*)&wd[c4] = *(const float4*)&wg[c4];
        }
        if (tid < NPAIR) pcnt[tid] = 0;
    }
    __syncthreads();

    const float* xrow = xs + pb * XSTR + q * QLEN;
    const float* wrow = ws + pn * XSTR + q * QLEN;

    // ---- pass 1: quarter max (branch-free) ----
    float m0 = NEG_INF, m1 = NEG_INF, m2 = NEG_INF, m3 = NEG_INF;
#pragma unroll 8
    for (int g = 0; g < QLEN / 4; ++g) {
        const float4 xv = *(const float4*)&xrow[g * 4];
        const float4 wv = *(const float4*)&wrow[g * 4];
        m0 = fmaxf(m0, xv.x + wv.x);
        m1 = fmaxf(m1, xv.y + wv.y);
        m2 = fmaxf(m2, xv.z + wv.z);
        m3 = fmaxf(m3, xv.w + wv.w);
    }
    qmax[tid] = fmaxf(fmaxf(m0, m1), fmaxf(m2, m3));
    __syncthreads();

    const float M   = fmaxf(fmaxf(qmax[p], qmax[64 + p]),
                            fmaxf(qmax[128 + p], qmax[192 + p]));
    const float thr = M - lam;

    // ---- pass 2: collect candidates z > thr (exact threshold, rare inserts) ----
#pragma unroll 4
    for (int g = 0; g < QLEN / 4; ++g) {
        const float4 xv = *(const float4*)&xrow[g * 4];
        const float4 wv = *(const float4*)&wrow[g * 4];
        const float z0 = xv.x + wv.x, z1 = xv.y + wv.y;
        const float z2 = xv.z + wv.z, z3 = xv.w + wv.w;
        const float gm = fmaxf(fmaxf(z0, z1), fmaxf(z2, z3));
        if (gm > thr) {
            if (z0 > thr) { int i = atomicAdd(&pcnt[p], 1); if (i < CAPP) cand[i * NPAIR + p] = z0; }
            if (z1 > thr) { int i = atomicAdd(&pcnt[p], 1); if (i < CAPP) cand[i * NPAIR + p] = z1; }
            if (z2 > thr) { int i = atomicAdd(&pcnt[p], 1); if (i < CAPP) cand[i * NPAIR + p] = z2; }
            if (z3 > thr) { int i = atomicAdd(&pcnt[p], 1); if (i < CAPP) cand[i * NPAIR + p] = z3; }
        }
    }
    __syncthreads();

    // ---- solve: one wave, thread-per-pair ----
    if (tid < NPAIR) {
        const int K = pcnt[p];
        float tau, delta;

        if (K <= CAPP) {
            // wave-uniform candidate-loop bound (typ ~10)
            int Kw = min(K, CAPP);
#pragma unroll
            for (int m = 1; m < 64; m <<= 1) Kw = max(Kw, __shfl_xor(Kw, m, 64));

            float lo = thr, hi = M;
            for (int it = 0; it < NB; ++it) {
                const float mid = 0.5f * (lo + hi);
                float f = 0.0f;
                for (int j = 0; j < Kw; ++j) {
                    float v = cand[j * NPAIR + p];
                    v = (j < K) ? v : NEG_INF;      // guard junk slots
                    f += fmaxf(v - mid, 0.0f);
                }
                if (f > lam) lo = mid; else hi = mid;
            }
            tau = 0.5f * (lo + hi);
            float s2 = 0.0f;
            for (int j = 0; j < Kw; ++j) {
                float v = cand[j * NPAIR + p];
                v = (j < K) ? v : NEG_INF;
                const float s = fmaxf(v - tau, 0.0f);
                s2 += s * s;
            }
            delta = s2 / (2.0f * lam);
        } else {
            // overflow fallback (~never): full-row bisection from LDS-resident tiles
            const float* xr = xs + pb * XSTR;
            const float* wr = ws + pn * XSTR;
            float lo = thr, hi = M;
            for (int it = 0; it < NB; ++it) {
                const float mid = 0.5f * (lo + hi);
                float f = 0.0f;
                for (int d = 0; d < D_DIM; d += 4) {
                    const float4 xv = *(const float4*)&xr[d];
                    const float4 wv = *(const float4*)&wr[d];
                    f += fmaxf(xv.x + wv.x - mid, 0.0f);
                    f += fmaxf(xv.y + wv.y - mid, 0.0f);
                    f += fmaxf(xv.z + wv.z - mid, 0.0f);
                    f += fmaxf(xv.w + wv.w - mid, 0.0f);
                }
                if (f > lam) lo = mid; else hi = mid;
            }
            tau = 0.5f * (lo + hi);
            float s2 = 0.0f;
            for (int d = 0; d < D_DIM; d += 4) {
                const float4 xv = *(const float4*)&xr[d];
                const float4 wv = *(const float4*)&wr[d];
                float s;
                s = fmaxf(xv.x + wv.x - tau, 0.0f); s2 += s * s;
                s = fmaxf(xv.y + wv.y - tau, 0.0f); s2 += s * s;
                s = fmaxf(xv.z + wv.z - tau, 0.0f); s2 += s * s;
                s = fmaxf(xv.w + wv.w - tau, 0.0f); s2 += s * s;
            }
            delta = s2 / (2.0f * lam);
        }

        const int ob = min(b0 + pb, B - 1);
        const int on = min(n0 + pn, N - 1);
        out[(size_t)ob * N + on] = tau + delta;
    }
}

extern "C" void kernel_launch(void* const* d_in, const int* in_sizes, int n_in,
                              void* d_out, int out_size, void* d_ws, size_t ws_size,
                              hipStream_t stream) {
    const float* x    = (const float*)d_in[0];
    const float* W    = (const float*)d_in[1];
    const float* lamp = (const float*)d_in[2];
    float* out        = (float*)d_out;

    const int B = in_sizes[0] / D_DIM;
    const int N = in_sizes[1] / D_DIM;

    dim3 grid((N + TNP - 1) / TNP, (B + TBP - 1) / TBP);
    moreau_tropical<<<grid, NTHR, 0, stream>>>(x, W, lamp, out, B, N);
}

// Round 5
// 82.869 us; speedup vs baseline: 11.9631x; 1.2506x over previous
//
#include <hip/hip_runtime.h>

// Moreau-tropical forward, round 5: register-resident operands, single z pass.
//
// z = x[b] + W[n] (D=1024); root of f(tau)=sum relu(z-tau)=lam lies in
// [M-lam, M], M=max(z); only z > M-lam contribute to any f(mid) there.
// Thread = (b-row, 32-elem interleaved d-slice in registers). Block = 8b x 8n.
// n-loop: W row L2->regs (double-buffered), z = x + w in regs (ONE pass:
// max via 5 shfl over the 32-lane half-wave, then exact-threshold candidate
// extraction from the same registers). Candidates -> small LDS buffer; final
// wave solves 64 pairs by bisection over <=CAPP candidates (round-4 proven).
// LDS = 8.5 KB (occupancy no longer LDS-capped); no LDS tile re-reads.

#define D_DIM   1024
#define TBP     8
#define TNP     8
#define NPAIR   64
#define NTHR    256
#define CAPP    32
#define NB      20
#define NEG_INF (-3.0e38f)

__global__ void __launch_bounds__(NTHR, 4)
moreau_tropical(const float* __restrict__ x, const float* __restrict__ W,
                const float* __restrict__ lam_p, float* __restrict__ out,
                int B, int N) {
    __shared__ float cand[CAPP * NPAIR];   // cand[j*64 + p], p in lanes -> conflict-free
    __shared__ float pmax[NPAIR];
    __shared__ int   pcnt[NPAIR];

    const int tid = threadIdx.x;
    const int s   = tid & 31;    // d-slice lane: owns d = g*128 + s*4 + {0..3}, g=0..7
    const int bl  = tid >> 5;    // b row 0..7 (wave = 2 b-rows x 32 slices)
    const int b0  = blockIdx.y * TBP;
    const int n0  = blockIdx.x * TNP;
    const float lam = lam_p[0];

    if (tid < NPAIR) pcnt[tid] = 0;
    __syncthreads();

    // x slice -> registers (once; coalesced 512B per g per half-wave; L3-hot)
    const float* xg = x + (size_t)min(b0 + bl, B - 1) * D_DIM;
    float4 xr[8];
#pragma unroll
    for (int g = 0; g < 8; ++g) xr[g] = *(const float4*)(xg + g * 128 + s * 4);

    float4 wa[8], wb[8];
    {
        const float* wg = W + (size_t)min(n0, N - 1) * D_DIM;
#pragma unroll
        for (int g = 0; g < 8; ++g) wa[g] = *(const float4*)(wg + g * 128 + s * 4);
    }

#define INS(v, pr)                                                             \
    if ((v) > thr) {                                                           \
        int i_ = atomicAdd(&pcnt[pr], 1);                                      \
        if (i_ < CAPP) cand[i_ * NPAIR + (pr)] = (v);                          \
    }

#define STEP(CUR, NXT, NL)                                                     \
    {                                                                          \
        const int nn = ((NL) + 1 < TNP) ? (NL) + 1 : (NL);                     \
        const float* wg_ = W + (size_t)min(n0 + nn, N - 1) * D_DIM;            \
        _Pragma("unroll")                                                      \
        for (int g = 0; g < 8; ++g)                                            \
            NXT[g] = *(const float4*)(wg_ + g * 128 + s * 4);  /* prefetch */  \
        float gmax[8];                                                         \
        _Pragma("unroll")                                                      \
        for (int g = 0; g < 8; ++g) {                                          \
            CUR[g].x += xr[g].x; CUR[g].y += xr[g].y;                          \
            CUR[g].z += xr[g].z; CUR[g].w += xr[g].w;                          \
            gmax[g] = fmaxf(fmaxf(CUR[g].x, CUR[g].y),                         \
                            fmaxf(CUR[g].z, CUR[g].w));                        \
        }                                                                      \
        float m_ = gmax[0];                                                    \
        _Pragma("unroll")                                                      \
        for (int g = 1; g < 8; ++g) m_ = fmaxf(m_, gmax[g]);                   \
        _Pragma("unroll")                                                      \
        for (int o = 1; o < 32; o <<= 1)                                       \
            m_ = fmaxf(m_, __shfl_xor(m_, o, 64));  /* halves independent */   \
        const int pr_ = bl * TNP + (NL);                                       \
        if (s == 0) pmax[pr_] = m_;                                            \
        const float thr = m_ - lam;                                            \
        _Pragma("unroll")                                                      \
        for (int g = 0; g < 8; ++g) {                                          \
            if (gmax[g] > thr) {                                               \
                INS(CUR[g].x, pr_); INS(CUR[g].y, pr_);                        \
                INS(CUR[g].z, pr_); INS(CUR[g].w, pr_);                        \
            }                                                                  \
        }                                                                      \
    }

#pragma unroll 1
    for (int nl = 0; nl < TNP; nl += 2) {
        STEP(wa, wb, nl);
        STEP(wb, wa, nl + 1);
    }
#undef STEP
#undef INS

    __syncthreads();

    // ---- solve: one wave, thread-per-pair (round-4 proven) ----
    if (tid < NPAIR) {
        const int p  = tid;
        const int pb = p >> 3;
        const int pn = p & 7;
        const int K  = pcnt[p];
        const float M   = pmax[p];
        const float thr = M - lam;
        float tau, delta;

        if (K <= CAPP) {
            int Kw = min(K, CAPP);
#pragma unroll
            for (int m = 1; m < 64; m <<= 1) Kw = max(Kw, __shfl_xor(Kw, m, 64));

            float lo = thr, hi = M;
            for (int it = 0; it < NB; ++it) {
                const float mid = 0.5f * (lo + hi);
                float f = 0.0f;
                for (int j = 0; j < Kw; ++j) {
                    float v = cand[j * NPAIR + p];
                    v = (j < K) ? v : NEG_INF;
                    f += fmaxf(v - mid, 0.0f);
                }
                if (f > lam) lo = mid; else hi = mid;
            }
            tau = 0.5f * (lo + hi);
            float s2 = 0.0f;
            for (int j = 0; j < Kw; ++j) {
                float v = cand[j * NPAIR + p];
                v = (j < K) ? v : NEG_INF;
                const float t = fmaxf(v - tau, 0.0f);
                s2 += t * t;
            }
            delta = s2 / (2.0f * lam);
        } else {
            // overflow fallback (~never): stream rows from global (L2/L3-hot)
            const float* xr_ = x + (size_t)min(b0 + pb, B - 1) * D_DIM;
            const float* wr_ = W + (size_t)min(n0 + pn, N - 1) * D_DIM;
            float lo = thr, hi = M;
            for (int it = 0; it < NB; ++it) {
                const float mid = 0.5f * (lo + hi);
                float f = 0.0f;
                for (int d = 0; d < D_DIM; ++d)
                    f += fmaxf(xr_[d] + wr_[d] - mid, 0.0f);
                if (f > lam) lo = mid; else hi = mid;
            }
            tau = 0.5f * (lo + hi);
            float s2 = 0.0f;
            for (int d = 0; d < D_DIM; ++d) {
                const float t = fmaxf(xr_[d] + wr_[d] - tau, 0.0f);
                s2 += t * t;
            }
            delta = s2 / (2.0f * lam);
        }

        const int ob = min(b0 + pb, B - 1);
        const int on = min(n0 + pn, N - 1);
        out[(size_t)ob * N + on] = tau + delta;
    }
}

extern "C" void kernel_launch(void* const* d_in, const int* in_sizes, int n_in,
                              void* d_out, int out_size, void* d_ws, size_t ws_size,
                              hipStream_t stream) {
    const float* x    = (const float*)d_in[0];
    const float* W    = (const float*)d_in[1];
    const float* lamp = (const float*)d_in[2];
    float* out        = (float*)d_out;

    const int B = in_sizes[0] / D_DIM;
    const int N = in_sizes[1] / D_DIM;

    dim3 grid((N + TNP - 1) / TNP, (B + TBP - 1) / TBP);
    moreau_tropical<<<grid, NTHR, 0, stream>>>(x, W, lamp, out, B, N);
}

// Round 6
// 80.191 us; speedup vs baseline: 12.3626x; 1.0334x over previous
//
#include <hip/hip_runtime.h>

// Moreau-tropical forward, round 6: wave-per-pair-step, 16 elems/lane,
// <=64 VGPR for 8 waves/SIMD occupancy.
//
// z = x[b] + W[n] (D=1024); root of f(tau)=sum relu(z-tau)=lam lies in
// [M-lam, M], M=max(z); only z > M-lam contribute to any f(mid) there.
// Block = 4 waves (one b-row each) x 8 n = 32 pairs; grid 2048 blocks
// (8 blocks/CU, 32 waves/CU — 2x round 5). Each wave: x slice in 4 float4
// regs (lane owns d = g*256 + lane*4 + 0..3), n-loop with double-buffered
// W rows in regs (one SGPR-base + lane*16 voffset + imm offsets). Single z
// pass: 64-lane shfl max -> exact thr = M - lam -> rare candidate inserts
// into 4 KB LDS. Final half-wave solves 32 pairs by register bisection.

#define D_DIM   1024
#define WB      4             // b-rows per block (one per wave)
#define WN      8             // n per block
#define NPAIR   32            // WB*WN
#define NTHR    256
#define CAPP    32
#define NB      16            // width-lam interval; y is 2nd-order insensitive
#define NEG_INF (-3.0e38f)

__global__ void __launch_bounds__(NTHR, 8)
moreau_tropical(const float* __restrict__ x, const float* __restrict__ W,
                const float* __restrict__ lam_p, float* __restrict__ out,
                int B, int N) {
    __shared__ float cand[CAPP * NPAIR];   // cand[j*32 + p]: conflict-free
    __shared__ float pmax[NPAIR];
    __shared__ int   pcnt[NPAIR];

    const int tid  = threadIdx.x;
    const int lane = tid & 63;
    const int w    = tid >> 6;            // wave id = b-row within block
    const int b0   = blockIdx.y * WB;
    const int n0   = blockIdx.x * WN;
    const float lam = lam_p[0];

    if (tid < NPAIR) pcnt[tid] = 0;
    __syncthreads();

    // x slice once (coalesced 1KB per wave per g; L2/L3-hot)
    const float* xg = x + (size_t)min(b0 + w, B - 1) * D_DIM + lane * 4;
    float4 xr[4];
#pragma unroll
    for (int g = 0; g < 4; ++g) xr[g] = *(const float4*)(xg + g * 256);

    float4 wa[4], wb_[4];
    {
        const float* wg = W + (size_t)min(n0, N - 1) * D_DIM + lane * 4;
#pragma unroll
        for (int g = 0; g < 4; ++g) wa[g] = *(const float4*)(wg + g * 256);
    }

#define INS(v)                                                        \
    if ((v) > thr) {                                                  \
        int i_ = atomicAdd(&pcnt[pr_], 1);                            \
        if (i_ < CAPP) cand[i_ * NPAIR + pr_] = (v);                  \
    }

#define STEP(CUR, NXT, NL)                                                    \
    {                                                                         \
        const int nn = ((NL) + 1 < WN) ? (NL) + 1 : (NL);                     \
        const float* wgn = W + (size_t)min(n0 + nn, N - 1) * D_DIM + lane * 4;\
        _Pragma("unroll")                                                     \
        for (int g = 0; g < 4; ++g)                                           \
            NXT[g] = *(const float4*)(wgn + g * 256);   /* prefetch */        \
        float gmax[4];                                                        \
        _Pragma("unroll")                                                     \
        for (int g = 0; g < 4; ++g) {                                         \
            CUR[g].x += xr[g].x; CUR[g].y += xr[g].y;                         \
            CUR[g].z += xr[g].z; CUR[g].w += xr[g].w;                         \
            gmax[g] = fmaxf(fmaxf(CUR[g].x, CUR[g].y),                        \
                            fmaxf(CUR[g].z, CUR[g].w));                       \
        }                                                                     \
        const float lmax = fmaxf(fmaxf(gmax[0], gmax[1]),                     \
                                 fmaxf(gmax[2], gmax[3]));                    \
        float m_ = lmax;                                                      \
        _Pragma("unroll")                                                     \
        for (int o = 1; o < 64; o <<= 1)                                      \
            m_ = fmaxf(m_, __shfl_xor(m_, o, 64));                            \
        const int pr_ = w * WN + (NL);                                        \
        if (lane == 0) pmax[pr_] = m_;                                        \
        const float thr = m_ - lam;                                           \
        if (lmax > thr) {            /* ~1-3 lanes per pair enter */          \
            _Pragma("unroll")                                                 \
            for (int g = 0; g < 4; ++g) {                                     \
                if (gmax[g] > thr) {                                          \
                    INS(CUR[g].x); INS(CUR[g].y);                             \
                    INS(CUR[g].z); INS(CUR[g].w);                             \
                }                                                             \
            }                                                                 \
        }                                                                     \
    }

#pragma unroll 1
    for (int nl = 0; nl < WN; nl += 2) {
        STEP(wa, wb_, nl);
        STEP(wb_, wa, nl + 1);
    }
#undef STEP
#undef INS

    __syncthreads();

    // ---- solve: half-wave, thread-per-pair (round-4/5 proven) ----
    if (tid < NPAIR) {
        const int p  = tid;
        const int pb = p >> 3;        // b-row (== wave id that produced it)
        const int pn = p & 7;
        const int K  = pcnt[p];
        const float M   = pmax[p];
        const float thr = M - lam;
        float tau, delta;

        if (K <= CAPP) {
            int Kw = K;
#pragma unroll
            for (int m = 1; m < 32; m <<= 1) Kw = max(Kw, __shfl_xor(Kw, m, 64));

            float lo = thr, hi = M;
            for (int it = 0; it < NB; ++it) {
                const float mid = 0.5f * (lo + hi);
                float f = 0.0f;
                for (int j = 0; j < Kw; ++j) {
                    float v = cand[j * NPAIR + p];
                    v = (j < K) ? v : NEG_INF;
                    f += fmaxf(v - mid, 0.0f);
                }
                if (f > lam) lo = mid; else hi = mid;
            }
            tau = 0.5f * (lo + hi);
            float s2 = 0.0f;
            for (int j = 0; j < Kw; ++j) {
                float v = cand[j * NPAIR + p];
                v = (j < K) ? v : NEG_INF;
                const float t = fmaxf(v - tau, 0.0f);
                s2 += t * t;
            }
            delta = s2 / (2.0f * lam);
        } else {
            // overflow fallback (~never): stream rows from global (L2/L3-hot)
            const float* xr_ = x + (size_t)min(b0 + pb, B - 1) * D_DIM;
            const float* wr_ = W + (size_t)min(n0 + pn, N - 1) * D_DIM;
            float lo = thr, hi = M;
            for (int it = 0; it < NB; ++it) {
                const float mid = 0.5f * (lo + hi);
                float f = 0.0f;
                for (int d = 0; d < D_DIM; ++d)
                    f += fmaxf(xr_[d] + wr_[d] - mid, 0.0f);
                if (f > lam) lo = mid; else hi = mid;
            }
            tau = 0.5f * (lo + hi);
            float s2 = 0.0f;
            for (int d = 0; d < D_DIM; ++d) {
                const float t = fmaxf(xr_[d] + wr_[d] - tau, 0.0f);
                s2 += t * t;
            }
            delta = s2 / (2.0f * lam);
        }

        const int ob = min(b0 + pb, B - 1);
        const int on = min(n0 + pn, N - 1);
        out[(size_t)ob * N + on] = tau + delta;
    }
}

extern "C" void kernel_launch(void* const* d_in, const int* in_sizes, int n_in,
                              void* d_out, int out_size, void* d_ws, size_t ws_size,
                              hipStream_t stream) {
    const float* x    = (const float*)d_in[0];
    const float* W    = (const float*)d_in[1];
    const float* lamp = (const float*)d_in[2];
    float* out        = (float*)d_out;

    const int B = in_sizes[0] / D_DIM;
    const int N = in_sizes[1] / D_DIM;

    dim3 grid((N + WN - 1) / WN, (B + WB - 1) / WB);
    moreau_tropical<<<grid, NTHR, 0, stream>>>(x, W, lamp, out, B, N);
}